// Round 3
// baseline (1494.191 us; speedup 1.0000x reference)
//
#include <hip/hip_runtime.h>
#include <hip/hip_bf16.h>
#include <math.h>

#define B_ 512
#define S_ 2048
#define E_DIM 64
#define P_DIM 32
#define H_DIM 64
#define CB_STRIDE 68  // 64 pc + mc + sc + ra + pad

typedef short s16x8 __attribute__((ext_vector_type(8)));
typedef int i32x4 __attribute__((ext_vector_type(4)));
typedef float f32x4 __attribute__((ext_vector_type(4)));

__device__ __forceinline__ float wave_reduce_sum(float v) {
#pragma unroll
  for (int m = 32; m >= 1; m >>= 1) v += __shfl_xor(v, m, 64);
  return v;
}

__device__ __forceinline__ float wave_reduce_max(float v) {
#pragma unroll
  for (int m = 32; m >= 1; m >>= 1) v = fmaxf(v, __shfl_xor(v, m, 64));
  return v;
}

__device__ __forceinline__ float tanh_fast(float x) {
  float e = __expf(2.0f * x);
  return 1.0f - 2.0f * __builtin_amdgcn_rcpf(e + 1.0f);
}

// fp32 -> bf16 bits with round-to-nearest-even (scalar; K0 only)
__device__ __forceinline__ short bf16b(float x) {
  union { float f; unsigned u; } a;
  a.f = x;
  unsigned r = (a.u + 0x7FFFu + ((a.u >> 16) & 1u)) >> 16;
  return (short)r;
}

// packed RNE convert: 2 fp32 -> 1 dword of 2 bf16 (v_cvt_pk_bf16_f32)
__device__ __forceinline__ int cvt_pk2(float a, float b) {
  union { __hip_bfloat162 v; int i; } u;
  u.v = __float22bfloat162_rn(make_float2(a, b));
  return u.i;
}

__device__ __forceinline__ s16x8 cvt8(float4 lo, float4 hi) {
  i32x4 r;
  r[0] = cvt_pk2(lo.x, lo.y);
  r[1] = cvt_pk2(lo.z, lo.w);
  r[2] = cvt_pk2(hi.x, hi.y);
  r[3] = cvt_pk2(hi.z, hi.w);
  return __builtin_bit_cast(s16x8, r);
}

// ---------------------------------------------------------------------------
// K0: per-launch precompute:
//   block 0: 12 bf16 B-fragments of [We;Wp] (MFMA layout) + zero counters
//   blocks 1..128: c_all[b,h] = bias[h] + sum_e target[b,e]*Wc[e,h]
// ---------------------------------------------------------------------------
__global__ __launch_bounds__(256) void precompute_kernel(
    const float* __restrict__ target_item, const float* __restrict__ Wp,
    const float* __restrict__ We, const float* __restrict__ Wc,
    const float* __restrict__ bias, s16x8* __restrict__ frags,
    float* __restrict__ c_all, unsigned* __restrict__ cnt) {
  const int tid = threadIdx.x;
  const int l = tid & 63;
  if (blockIdx.x == 0) {
    cnt[tid] = 0u;        // counters are in poisoned workspace: zero each
    cnt[256 + tid] = 0u;  // launch (512 total)
    const int w = tid >> 6;
    const int cc = l & 15;
    const int q = l >> 4;
#pragma unroll
    for (int i = 0; i < 3; ++i) {
      const int f = w * 3 + i;
      const int kstep = f >> 2;
      const int nt = f & 3;
      const float* __restrict__ src =
          (kstep < 2)
              ? (We + (size_t)(kstep * 32 + q * 8) * H_DIM + nt * 16 + cc)
              : (Wp + (size_t)(q * 8) * H_DIM + nt * 16 + cc);
      s16x8 v;
#pragma unroll
      for (int j = 0; j < 8; ++j) v[j] = bf16b(src[(size_t)j * H_DIM]);
      frags[f * 64 + l] = v;
    }
  } else {
    const int b = (blockIdx.x - 1) * 4 + (tid >> 6);
    const int h = l;
    const float* __restrict__ tg = target_item + b * E_DIM;
    float c = bias[h];
#pragma unroll
    for (int e = 0; e < 64; ++e) c = fmaf(tg[e], Wc[e * H_DIM + h], c);
    c_all[b * H_DIM + h] = c;
  }
}

// ---------------------------------------------------------------------------
// K1: barrier-free. Each WAVE owns a 32-row chunk (64 chunks per b):
//   scores (2x 16-row MFMA tiles) -> per-wave softmax partials (mc, sc, ra)
//   entirely via butterfly shuffles (values replicated x16 within q-groups;
//   corrected by exact *1/16) -> weights via private 32-float LDS slice
//   (same-wave RAW, no __syncthreads) -> pc[e] = sum w*items (L2-hot reload)
//   -> per-wave chunk record. Last-arriving wave per b (device-scope atomic
//   ticket) performs the online-softmax combine and writes out.
//   L==0: uniform path (all rows valid, score 0, ra forced 0).
// ---------------------------------------------------------------------------
__global__ __launch_bounds__(256) void scores_mfma_kernel(
    const float* __restrict__ seq_items, const float* __restrict__ seq_pos,
    const float* __restrict__ z, const int* __restrict__ seq_len,
    const s16x8* __restrict__ frags, const float* __restrict__ c_all,
    float* __restrict__ chunk_buf, unsigned* __restrict__ cnt,
    float* __restrict__ out) {
  const int blk = blockIdx.x;
  const int b = blk >> 4;          // 16 blocks (x4 wave-chunks) per b
  const int s0 = (blk & 15) << 7;
  const int L = seq_len[b];
  const bool uni = (L == 0);
  if (!uni && s0 >= L) return;

  __shared__ float s_w[128];  // 32 floats per wave, private slices

  const int tid = threadIdx.x;
  const int l = tid & 63;
  const int w = tid >> 6;
  const int cc = l & 15;  // col within 16 (h-within-tile; also row m for A)
  const int q = l >> 4;   // quad -> k-chunk (and row-group for C/D)
  const int rowbase = s0 + w * 32;
  const int cw = ((blk & 15) << 2) | w;  // chunk id within b: 0..63
  float* __restrict__ cb = chunk_buf + ((size_t)b * 64 + cw) * CB_STRIDE;

  const bool waveActive = uni || (rowbase < L);
  if (waveActive) {
    const float* __restrict__ itemsB = seq_items + (size_t)b * S_ * E_DIM;
    const float* __restrict__ posB = seq_pos + (size_t)b * S_ * P_DIM;

    // ---- issue HBM A-loads first (longest latency) ----
    float4 xi[2][4];
    float4 xp[2][2];
#pragma unroll
    for (int mt = 0; mt < 2; ++mt) {
      const int s = rowbase + mt * 16 + cc;
      const float* __restrict__ pi = itemsB + (size_t)s * E_DIM + q * 8;
      xi[mt][0] = ((const float4*)pi)[0];
      xi[mt][1] = ((const float4*)pi)[1];
      xi[mt][2] = ((const float4*)(pi + 32))[0];
      xi[mt][3] = ((const float4*)(pi + 32))[1];
      const float* __restrict__ pp = posB + (size_t)s * P_DIM + q * 8;
      xp[mt][0] = ((const float4*)pp)[0];
      xp[mt][1] = ((const float4*)pp)[1];
    }

    // ---- L2-hot operand loads ----
    s16x8 bfr[12];
#pragma unroll
    for (int f = 0; f < 12; ++f) bfr[f] = frags[f * 64 + l];
    float ch[4], zh[4];
#pragma unroll
    for (int nt = 0; nt < 4; ++nt) {
      const int h = nt * 16 + cc;
      ch[nt] = c_all[b * H_DIM + h];
      zh[nt] = z[h];
    }

    s16x8 afr[2][3];
#pragma unroll
    for (int mt = 0; mt < 2; ++mt) {
      afr[mt][0] = cvt8(xi[mt][0], xi[mt][1]);
      afr[mt][1] = cvt8(xi[mt][2], xi[mt][3]);
      afr[mt][2] = cvt8(xp[mt][0], xp[mt][1]);
    }

    float asum[2][4];
#pragma unroll
    for (int mt = 0; mt < 2; ++mt) {
      f32x4 acc[4] = {};
#pragma unroll
      for (int kk = 0; kk < 2; ++kk) {
#pragma unroll
        for (int nt = 0; nt < 4; ++nt)
          acc[nt] = __builtin_amdgcn_mfma_f32_16x16x32_bf16(
              afr[mt][kk], bfr[kk * 4 + nt], acc[nt], 0, 0, 0);
      }
#pragma unroll
      for (int nt = 0; nt < 4; ++nt)
        acc[nt] = __builtin_amdgcn_mfma_f32_16x16x32_bf16(
            afr[mt][2], bfr[8 + nt], acc[nt], 0, 0, 0);

      // tanh + z, reduce over h: butterfly within 16-lane groups leaves the
      // row-sum replicated in ALL 16 lanes of each q-group.
#pragma unroll
      for (int r = 0; r < 4; ++r) {
        float t = tanh_fast(acc[0][r] + ch[0]) * zh[0];
        t += tanh_fast(acc[1][r] + ch[1]) * zh[1];
        t += tanh_fast(acc[2][r] + ch[2]) * zh[2];
        t += tanh_fast(acc[3][r] + ch[3]) * zh[3];
#pragma unroll
        for (int m = 8; m >= 1; m >>= 1) t += __shfl_xor(t, m, 64);
        asum[mt][r] = t;  // score of row rowbase + mt*16 + q*4 + r
      }
    }

    // ---- per-wave softmax partials over this wave's 32 rows ----
    float mx = -INFINITY, racc = 0.0f;
    float ae[2][4];
#pragma unroll
    for (int mt = 0; mt < 2; ++mt) {
#pragma unroll
      for (int r = 0; r < 4; ++r) {
        const int srow = rowbase + mt * 16 + q * 4 + r;
        const bool valid = uni || (srow < L);
        ae[mt][r] = uni ? 0.0f : (valid ? asum[mt][r] : -INFINITY);
        racc += (!uni && valid) ? asum[mt][r] : 0.0f;
        mx = fmaxf(mx, ae[mt][r]);
      }
    }
    mx = wave_reduce_max(mx);  // finite: rowbase < L (or uni) => >=1 valid row
    float wgt[2][4];
    float wsum = 0.0f;
#pragma unroll
    for (int mt = 0; mt < 2; ++mt) {
#pragma unroll
      for (int r = 0; r < 4; ++r) {
        wgt[mt][r] = __expf(ae[mt][r] - mx);  // invalid: exp(-inf)=0
        wsum += wgt[mt][r];
      }
    }
    // values replicated x16 within q-groups: 1/16 correction is exact
    const float scv = wave_reduce_sum(wsum) * 0.0625f;
    const float rav = wave_reduce_sum(racc) * 0.0625f;

    // ---- park weights in this wave's private LDS slice (no barrier) ----
    if (cc == 0) {
#pragma unroll
      for (int mt = 0; mt < 2; ++mt)
#pragma unroll
        for (int r = 0; r < 4; ++r)
          s_w[w * 32 + mt * 16 + q * 4 + r] = wgt[mt][r];
    }

    // ---- pc[e] = sum over 32 rows of w[row]*items[row,e] (L2-hot) ----
    const float4* __restrict__ ip4 = (const float4*)itemsB;
    float4 a4 = make_float4(0.f, 0.f, 0.f, 0.f);
#pragma unroll
    for (int i = 0; i < 8; ++i) {
      const int rloc = q + i * 4;  // q is this lane's row-group 0..3
      const float g = s_w[w * 32 + rloc];
      const float4 x = ip4[(size_t)(rowbase + rloc) * 16 + cc];
      a4.x = fmaf(g, x.x, a4.x);
      a4.y = fmaf(g, x.y, a4.y);
      a4.z = fmaf(g, x.z, a4.z);
      a4.w = fmaf(g, x.w, a4.w);
    }
#pragma unroll
    for (int m = 16; m <= 32; m <<= 1) {
      a4.x += __shfl_xor(a4.x, m, 64);
      a4.y += __shfl_xor(a4.y, m, 64);
      a4.z += __shfl_xor(a4.z, m, 64);
      a4.w += __shfl_xor(a4.w, m, 64);
    }
    if (q == 0) *(float4*)(cb + cc * 4) = a4;  // 16 lanes x float4 = pc[64]
    if (l == 16) cb[64] = mx;
    if (l == 17) cb[65] = scv;
    if (l == 18) cb[66] = rav;
  } else {
    // wave's rows entirely >= L: empty chunk record
    if (l < 16) {
      f32x4 zz = {};
      *(f32x4*)(cb + l * 4) = zz;
    }
    if (l == 16) cb[64] = -INFINITY;
    if (l == 17) cb[65] = 0.0f;
    if (l == 18) cb[66] = 0.0f;
  }

  // ---- last-arriver ticket: the final wave of b does the combine ----
  __threadfence();
  const int nch = uni ? 16 : ((L + 127) >> 7);
  const unsigned expected = (unsigned)(nch << 2);  // 4 waves per block
  unsigned old = 0;
  if (l == 0) old = atomicAdd(&cnt[b], 1u);
  old = (unsigned)__shfl((int)old, 0, 64);
  if (old == expected - 1u) {
    __threadfence();
    const float* __restrict__ cbb = chunk_buf + (size_t)b * 64 * CB_STRIDE;
    float m = -INFINITY;
    for (int c = 0; c < (int)expected; ++c)
      m = fmaxf(m, cbb[c * CB_STRIDE + 64]);
    float u = 0.0f, den = 0.0f, rsum = 0.0f;
    for (int c = 0; c < (int)expected; ++c) {
      const float e = __expf(cbb[c * CB_STRIDE + 64] - m);
      u = fmaf(e, cbb[c * CB_STRIDE + l], u);
      den = fmaf(e, cbb[c * CB_STRIDE + 65], den);
      rsum += cbb[c * CB_STRIDE + 66];
    }
    out[b * E_DIM + l] = u / den;
    if (l == 0) out[B_ * E_DIM + b] = rsum;
  }
}

extern "C" void kernel_launch(void* const* d_in, const int* in_sizes, int n_in,
                              void* d_out, int out_size, void* d_ws, size_t ws_size,
                              hipStream_t stream) {
  const float* seq_items = (const float*)d_in[0];
  const float* seq_pos = (const float*)d_in[1];
  const float* target_item = (const float*)d_in[2];
  const float* Wp = (const float*)d_in[3];
  const float* We = (const float*)d_in[4];
  const float* Wc = (const float*)d_in[5];
  const float* bias = (const float*)d_in[6];
  const float* z = (const float*)d_in[7];
  const int* seq_len = (const int*)d_in[8];
  float* out = (float*)d_out;

  // workspace (floats): chunk_buf[512*64*68] | c_all[512*64] | frags | cnt
  float* chunk_buf = (float*)d_ws;
  float* c_all = chunk_buf + (size_t)B_ * 64 * CB_STRIDE;
  float* frags_f = c_all + (size_t)B_ * H_DIM;
  s16x8* frags = (s16x8*)frags_f;
  unsigned* cnt = (unsigned*)(frags_f + 12 * 64 * 4);  // 12*64 s16x8 = 3072 fl

  precompute_kernel<<<129, 256, 0, stream>>>(target_item, Wp, We, Wc, bias,
                                             frags, c_all, cnt);
  scores_mfma_kernel<<<B_ * 16, 256, 0, stream>>>(seq_items, seq_pos, z,
                                                  seq_len, frags, c_all,
                                                  chunk_buf, cnt, out);
}

// Round 4
// 455.306 us; speedup vs baseline: 3.2817x; 3.2817x over previous
//
#include <hip/hip_runtime.h>
#include <hip/hip_bf16.h>
#include <math.h>

#define B_ 512
#define S_ 2048
#define E_DIM 64
#define P_DIM 32
#define H_DIM 64
#define CB_STRIDE 68  // 64 pc + mc + sc + ra + pad

typedef short s16x8 __attribute__((ext_vector_type(8)));
typedef int i32x4 __attribute__((ext_vector_type(4)));
typedef float f32x4 __attribute__((ext_vector_type(4)));

__device__ __forceinline__ float wave_reduce_sum(float v) {
#pragma unroll
  for (int m = 32; m >= 1; m >>= 1) v += __shfl_xor(v, m, 64);
  return v;
}

__device__ __forceinline__ float wave_reduce_max(float v) {
#pragma unroll
  for (int m = 32; m >= 1; m >>= 1) v = fmaxf(v, __shfl_xor(v, m, 64));
  return v;
}

__device__ __forceinline__ float tanh_fast(float x) {
  float e = __expf(2.0f * x);
  return 1.0f - 2.0f * __builtin_amdgcn_rcpf(e + 1.0f);
}

// fp32 -> bf16 bits with round-to-nearest-even (scalar; K0 only)
__device__ __forceinline__ short bf16b(float x) {
  union { float f; unsigned u; } a;
  a.f = x;
  unsigned r = (a.u + 0x7FFFu + ((a.u >> 16) & 1u)) >> 16;
  return (short)r;
}

// packed RNE convert: 2 fp32 -> 1 dword of 2 bf16 (v_cvt_pk_bf16_f32)
__device__ __forceinline__ int cvt_pk2(float a, float b) {
  union { __hip_bfloat162 v; int i; } u;
  u.v = __float22bfloat162_rn(make_float2(a, b));
  return u.i;
}

__device__ __forceinline__ s16x8 cvt8(float4 lo, float4 hi) {
  i32x4 r;
  r[0] = cvt_pk2(lo.x, lo.y);
  r[1] = cvt_pk2(lo.z, lo.w);
  r[2] = cvt_pk2(hi.x, hi.y);
  r[3] = cvt_pk2(hi.z, hi.w);
  return __builtin_bit_cast(s16x8, r);
}

// ---------------------------------------------------------------------------
// K0: per-launch precompute:
//   block 0: 12 bf16 B-fragments of [We;Wp] (MFMA layout)
//   blocks 1..128: c_all[b,h] = bias[h] + sum_e target[b,e]*Wc[e,h]
// ---------------------------------------------------------------------------
__global__ __launch_bounds__(256) void precompute_kernel(
    const float* __restrict__ target_item, const float* __restrict__ Wp,
    const float* __restrict__ We, const float* __restrict__ Wc,
    const float* __restrict__ bias, s16x8* __restrict__ frags,
    float* __restrict__ c_all) {
  const int tid = threadIdx.x;
  const int l = tid & 63;
  if (blockIdx.x == 0) {
    const int w = tid >> 6;
    const int cc = l & 15;
    const int q = l >> 4;
#pragma unroll
    for (int i = 0; i < 3; ++i) {
      const int f = w * 3 + i;
      const int kstep = f >> 2;
      const int nt = f & 3;
      const float* __restrict__ src =
          (kstep < 2)
              ? (We + (size_t)(kstep * 32 + q * 8) * H_DIM + nt * 16 + cc)
              : (Wp + (size_t)(q * 8) * H_DIM + nt * 16 + cc);
      s16x8 v;
#pragma unroll
      for (int j = 0; j < 8; ++j) v[j] = bf16b(src[(size_t)j * H_DIM]);
      frags[f * 64 + l] = v;
    }
  } else {
    const int b = (blockIdx.x - 1) * 4 + (tid >> 6);
    const int h = l;
    const float* __restrict__ tg = target_item + b * E_DIM;
    float c = bias[h];
#pragma unroll
    for (int e = 0; e < 64; ++e) c = fmaf(tg[e], Wc[e * H_DIM + h], c);
    c_all[b * H_DIM + h] = c;
  }
}

// ---------------------------------------------------------------------------
// K1: barrier-free, fence-free. Each WAVE owns a 64-row chunk (32 per b).
//   Two pipelined 2-tile batches: batch-B loads issued before batch-A
//   compute so the tanh epilogue hides the second HBM wait.
//   Per-wave softmax partials via butterfly shuffles (row-sums replicated
//   x16 within q-groups; corrected by exact *1/16); weights parked in a
//   private 64-float LDS slice (same-wave RAW, no __syncthreads);
//   pc[e] = sum w*items re-read L2-hot. One 68-float record per wave.
//   A wave's record is read by K2 iff cw < ceil(L/64), so inactive waves
//   just return. L==0: uniform path (score 0 everywhere, ra forced 0).
// ---------------------------------------------------------------------------
__global__ __launch_bounds__(256) void scores_mfma_kernel(
    const float* __restrict__ seq_items, const float* __restrict__ seq_pos,
    const float* __restrict__ z, const int* __restrict__ seq_len,
    const s16x8* __restrict__ frags, const float* __restrict__ c_all,
    float* __restrict__ chunk_buf) {
  const int blk = blockIdx.x;
  const int b = blk >> 3;          // 8 blocks (x4 wave-chunks of 64) per b
  const int s0 = (blk & 7) << 8;
  const int L = seq_len[b];
  const bool uni = (L == 0);
  if (!uni && s0 >= L) return;

  __shared__ float s_w[256];  // 64 floats per wave, private slices

  const int tid = threadIdx.x;
  const int l = tid & 63;
  const int w = tid >> 6;
  const int cc = l & 15;  // col within 16 (h-within-tile; also row m for A)
  const int q = l >> 4;   // quad -> k-chunk (and row-group for C/D)
  const int rowbase = s0 + w * 64;
  const int cw = ((blk & 7) << 2) | w;  // chunk id within b: 0..31

  if (!uni && rowbase >= L) return;  // K2 never reads this record

  float* __restrict__ cb = chunk_buf + ((size_t)b * 32 + cw) * CB_STRIDE;
  const float* __restrict__ itemsB = seq_items + (size_t)b * S_ * E_DIM;
  const float* __restrict__ posB = seq_pos + (size_t)b * S_ * P_DIM;

  // ---- batch A (tiles 0,1): issue HBM loads first ----
  float4 xiA[2][4], xpA[2][2];
#pragma unroll
  for (int mt = 0; mt < 2; ++mt) {
    const int s = rowbase + mt * 16 + cc;
    const float* __restrict__ pi = itemsB + (size_t)s * E_DIM + q * 8;
    xiA[mt][0] = ((const float4*)pi)[0];
    xiA[mt][1] = ((const float4*)pi)[1];
    xiA[mt][2] = ((const float4*)(pi + 32))[0];
    xiA[mt][3] = ((const float4*)(pi + 32))[1];
    const float* __restrict__ pp = posB + (size_t)s * P_DIM + q * 8;
    xpA[mt][0] = ((const float4*)pp)[0];
    xpA[mt][1] = ((const float4*)pp)[1];
  }
  // ---- batch B (tiles 2,3): issue loads before any compute ----
  float4 xiB[2][4], xpB[2][2];
#pragma unroll
  for (int mt = 0; mt < 2; ++mt) {
    const int s = rowbase + 32 + mt * 16 + cc;
    const float* __restrict__ pi = itemsB + (size_t)s * E_DIM + q * 8;
    xiB[mt][0] = ((const float4*)pi)[0];
    xiB[mt][1] = ((const float4*)pi)[1];
    xiB[mt][2] = ((const float4*)(pi + 32))[0];
    xiB[mt][3] = ((const float4*)(pi + 32))[1];
    const float* __restrict__ pp = posB + (size_t)s * P_DIM + q * 8;
    xpB[mt][0] = ((const float4*)pp)[0];
    xpB[mt][1] = ((const float4*)pp)[1];
  }

  // ---- L2-hot operand loads ----
  s16x8 bfr[12];
#pragma unroll
  for (int f = 0; f < 12; ++f) bfr[f] = frags[f * 64 + l];
  float ch[4], zh[4];
#pragma unroll
  for (int nt = 0; nt < 4; ++nt) {
    const int h = nt * 16 + cc;
    ch[nt] = c_all[b * H_DIM + h];
    zh[nt] = z[h];
  }

  float asum[4][4];  // [tile][r] row-sum, replicated across 16-lane groups

  // ---- compute batch A (epilogue hides batch-B load latency) ----
#pragma unroll
  for (int mt = 0; mt < 2; ++mt) {
    s16x8 a0 = cvt8(xiA[mt][0], xiA[mt][1]);
    s16x8 a1 = cvt8(xiA[mt][2], xiA[mt][3]);
    s16x8 a2 = cvt8(xpA[mt][0], xpA[mt][1]);
    f32x4 acc[4] = {};
#pragma unroll
    for (int nt = 0; nt < 4; ++nt) {
      acc[nt] = __builtin_amdgcn_mfma_f32_16x16x32_bf16(a0, bfr[nt], acc[nt], 0, 0, 0);
      acc[nt] = __builtin_amdgcn_mfma_f32_16x16x32_bf16(a1, bfr[4 + nt], acc[nt], 0, 0, 0);
      acc[nt] = __builtin_amdgcn_mfma_f32_16x16x32_bf16(a2, bfr[8 + nt], acc[nt], 0, 0, 0);
    }
#pragma unroll
    for (int r = 0; r < 4; ++r) {
      float t = tanh_fast(acc[0][r] + ch[0]) * zh[0];
      t += tanh_fast(acc[1][r] + ch[1]) * zh[1];
      t += tanh_fast(acc[2][r] + ch[2]) * zh[2];
      t += tanh_fast(acc[3][r] + ch[3]) * zh[3];
#pragma unroll
      for (int m = 8; m >= 1; m >>= 1) t += __shfl_xor(t, m, 64);
      asum[mt][r] = t;
    }
  }
  // ---- compute batch B ----
#pragma unroll
  for (int mt = 0; mt < 2; ++mt) {
    s16x8 a0 = cvt8(xiB[mt][0], xiB[mt][1]);
    s16x8 a1 = cvt8(xiB[mt][2], xiB[mt][3]);
    s16x8 a2 = cvt8(xpB[mt][0], xpB[mt][1]);
    f32x4 acc[4] = {};
#pragma unroll
    for (int nt = 0; nt < 4; ++nt) {
      acc[nt] = __builtin_amdgcn_mfma_f32_16x16x32_bf16(a0, bfr[nt], acc[nt], 0, 0, 0);
      acc[nt] = __builtin_amdgcn_mfma_f32_16x16x32_bf16(a1, bfr[4 + nt], acc[nt], 0, 0, 0);
      acc[nt] = __builtin_amdgcn_mfma_f32_16x16x32_bf16(a2, bfr[8 + nt], acc[nt], 0, 0, 0);
    }
#pragma unroll
    for (int r = 0; r < 4; ++r) {
      float t = tanh_fast(acc[0][r] + ch[0]) * zh[0];
      t += tanh_fast(acc[1][r] + ch[1]) * zh[1];
      t += tanh_fast(acc[2][r] + ch[2]) * zh[2];
      t += tanh_fast(acc[3][r] + ch[3]) * zh[3];
#pragma unroll
      for (int m = 8; m >= 1; m >>= 1) t += __shfl_xor(t, m, 64);
      asum[2 + mt][r] = t;
    }
  }

  // ---- per-wave softmax partials over this wave's 64 rows ----
  // lane's asum[mt][r] is score of row rowbase + mt*16 + q*4 + r
  float mx = -INFINITY, racc = 0.0f;
  float ae[4][4];
#pragma unroll
  for (int mt = 0; mt < 4; ++mt) {
#pragma unroll
    for (int r = 0; r < 4; ++r) {
      const int srow = rowbase + mt * 16 + q * 4 + r;
      const bool valid = uni || (srow < L);
      ae[mt][r] = uni ? 0.0f : (valid ? asum[mt][r] : -INFINITY);
      racc += (!uni && valid) ? asum[mt][r] : 0.0f;
      mx = fmaxf(mx, ae[mt][r]);
    }
  }
  mx = wave_reduce_max(mx);  // finite: rowbase < L (or uni) => >=1 valid row
  float wgt[4][4];
  float wsum = 0.0f;
#pragma unroll
  for (int mt = 0; mt < 4; ++mt) {
#pragma unroll
    for (int r = 0; r < 4; ++r) {
      wgt[mt][r] = __expf(ae[mt][r] - mx);  // invalid rows: exp(-inf)=0
      wsum += wgt[mt][r];
    }
  }
  // values replicated x16 within q-groups: 1/16 correction is exact
  const float scv = wave_reduce_sum(wsum) * 0.0625f;
  const float rav = wave_reduce_sum(racc) * 0.0625f;

  // ---- park weights in this wave's private LDS slice (no barrier) ----
  if (cc == 0) {
#pragma unroll
    for (int mt = 0; mt < 4; ++mt)
#pragma unroll
      for (int r = 0; r < 4; ++r)
        s_w[w * 64 + mt * 16 + q * 4 + r] = wgt[mt][r];
  }

  // ---- pc[e] = sum over 64 rows of w[row]*items[row,e] (L2-hot) ----
  const float4* __restrict__ ip4 = (const float4*)itemsB;
  float4 a4 = make_float4(0.f, 0.f, 0.f, 0.f);
#pragma unroll
  for (int i = 0; i < 16; ++i) {
    const int rloc = q + i * 4;  // q is this lane's row-group 0..3
    const float g = s_w[w * 64 + rloc];
    const float4 x = ip4[(size_t)(rowbase + rloc) * 16 + cc];
    a4.x = fmaf(g, x.x, a4.x);
    a4.y = fmaf(g, x.y, a4.y);
    a4.z = fmaf(g, x.z, a4.z);
    a4.w = fmaf(g, x.w, a4.w);
  }
#pragma unroll
  for (int m = 16; m <= 32; m <<= 1) {
    a4.x += __shfl_xor(a4.x, m, 64);
    a4.y += __shfl_xor(a4.y, m, 64);
    a4.z += __shfl_xor(a4.z, m, 64);
    a4.w += __shfl_xor(a4.w, m, 64);
  }
  if (q == 0) *(float4*)(cb + cc * 4) = a4;  // 16 lanes x float4 = pc[64]
  if (l == 16) cb[64] = mx;
  if (l == 17) cb[65] = scv;
  if (l == 18) cb[66] = rav;
}

// ---------------------------------------------------------------------------
// K2: per-b combine of chunk partials (online-softmax merge).
//   m = max_c mc; u = sum_c pc*e^{mc-m} / sum_c sc*e^{mc-m}; r = sum_c ra.
// Grid: B_ blocks x 64 threads. Reads only records c < nc (all written).
// ---------------------------------------------------------------------------
__global__ __launch_bounds__(64) void combine_kernel(
    const float* __restrict__ chunk_buf, const int* __restrict__ seq_len,
    float* __restrict__ out) {
  const int b = blockIdx.x;
  const int t = threadIdx.x;
  const int L = seq_len[b];
  const int nc = (L == 0) ? 32 : ((L + 63) >> 6);
  const float* __restrict__ cb = chunk_buf + (size_t)b * 32 * CB_STRIDE;

  float m = -INFINITY;
  for (int c = 0; c < nc; ++c) m = fmaxf(m, cb[c * CB_STRIDE + 64]);
  float u = 0.0f, den = 0.0f, r = 0.0f;
  for (int c = 0; c < nc; ++c) {
    const float e = __expf(cb[c * CB_STRIDE + 64] - m);
    u = fmaf(e, cb[c * CB_STRIDE + t], u);
    den = fmaf(e, cb[c * CB_STRIDE + 65], den);
    r += cb[c * CB_STRIDE + 66];
  }
  out[b * E_DIM + t] = u / den;
  if (t == 0) out[B_ * E_DIM + b] = r;
}

extern "C" void kernel_launch(void* const* d_in, const int* in_sizes, int n_in,
                              void* d_out, int out_size, void* d_ws, size_t ws_size,
                              hipStream_t stream) {
  const float* seq_items = (const float*)d_in[0];
  const float* seq_pos = (const float*)d_in[1];
  const float* target_item = (const float*)d_in[2];
  const float* Wp = (const float*)d_in[3];
  const float* We = (const float*)d_in[4];
  const float* Wc = (const float*)d_in[5];
  const float* bias = (const float*)d_in[6];
  const float* z = (const float*)d_in[7];
  const int* seq_len = (const int*)d_in[8];
  float* out = (float*)d_out;

  // workspace (floats): chunk_buf[512*32*68] | c_all[512*64] | frags
  float* chunk_buf = (float*)d_ws;
  float* c_all = chunk_buf + (size_t)B_ * 32 * CB_STRIDE;
  float* frags_f = c_all + (size_t)B_ * H_DIM;
  s16x8* frags = (s16x8*)frags_f;

  precompute_kernel<<<129, 256, 0, stream>>>(target_item, Wp, We, Wc, bias,
                                             frags, c_all);
  scores_mfma_kernel<<<B_ * 8, 256, 0, stream>>>(seq_items, seq_pos, z,
                                                 seq_len, frags, c_all,
                                                 chunk_buf);
  combine_kernel<<<B_, 64, 0, stream>>>(chunk_buf, seq_len, out);
}